// Round 2
// baseline (1832.100 us; speedup 1.0000x reference)
//
#include <hip/hip_runtime.h>
#include <hip/hip_bf16.h>
#include <math.h>

namespace {
constexpr int kB = 2, kN = 2048, kDIM = 1536, kH = 8, kDK = 64, kDV = 192;
constexpr int kHDK = kH * kDK;   // 512
constexpr int kHDV = kH * kDV;   // 1536
constexpr float kScale = 0.125f; // DK^-0.5
}

// bf16 helpers (RNE pack, cheap unpack)
__device__ __forceinline__ unsigned short f2b(float f) {
    union { float f; unsigned u; } v; v.f = f;
    unsigned r = (v.u + 0x7FFFu + ((v.u >> 16) & 1u)) >> 16;
    return (unsigned short)r;
}
__device__ __forceinline__ float b2f(unsigned short u) {
    union { unsigned u; float f; } v; v.u = ((unsigned)u) << 16; return v.f;
}
__device__ __forceinline__ float2 up2(unsigned w) {   // two bf16 in one u32
    union { unsigned u; float f; } a, b; a.u = w << 16; b.u = w & 0xFFFF0000u;
    return make_float2(a.f, b.f);
}

// ---------------------------------------------------------------------------
// Fused QKV projection: Y = x @ [Wq | Wk | Wv].
// Q written fp32 (scaled); K,V written bf16. 128x128 tile, BK=16, 256 thr.
// ---------------------------------------------------------------------------
__global__ __launch_bounds__(256) void qkv_gemm(
    const float* __restrict__ x,
    const float* __restrict__ Wq,
    const float* __restrict__ Wk,
    const float* __restrict__ Wv,
    float* __restrict__ qo, unsigned short* __restrict__ ko,
    unsigned short* __restrict__ vo)
{
    __shared__ float As[16][132];
    __shared__ float Bs[16][132];
    const int tid = threadIdx.x;
    const int bm  = blockIdx.y * 128;
    const int bng = blockIdx.x * 128;

    const float* Wp; int ldw, nn0, hd; bool is_q; unsigned short* o16;
    if (bng < kHDK)            { Wp = Wq; ldw = kHDK; nn0 = bng;          hd = kDK; is_q = true;  o16 = nullptr; }
    else if (bng < 2 * kHDK)   { Wp = Wk; ldw = kHDK; nn0 = bng - kHDK;   hd = kDK; is_q = false; o16 = ko; }
    else                       { Wp = Wv; ldw = kHDV; nn0 = bng - 2*kHDK; hd = kDV; is_q = false; o16 = vo; }

    const int tx = tid & 15, ty = tid >> 4;
    const int ar = tid >> 2, ac = (tid & 3) << 2;
    const int wr = tid >> 5, wc = (tid & 31) << 2;

    const float* xA  = x + (size_t)(bm + ar) * kDIM + ac;
    const float* xA2 = x + (size_t)(bm + 64 + ar) * kDIM + ac;
    const float* wB  = Wp + (size_t)wr * ldw + nn0 + wc;
    const float* wB2 = Wp + (size_t)(wr + 8) * ldw + nn0 + wc;

    float4 av0 = *(const float4*)xA;
    float4 av1 = *(const float4*)xA2;
    float4 wv0 = *(const float4*)wB;
    float4 wv1 = *(const float4*)wB2;

    float acc[8][8];
#pragma unroll
    for (int i = 0; i < 8; ++i)
#pragma unroll
        for (int j = 0; j < 8; ++j) acc[i][j] = 0.f;

    for (int k0 = 0; k0 < kDIM; k0 += 16) {
        __syncthreads();
        As[ac+0][ar]    = av0.x; As[ac+1][ar]    = av0.y; As[ac+2][ar]    = av0.z; As[ac+3][ar]    = av0.w;
        As[ac+0][64+ar] = av1.x; As[ac+1][64+ar] = av1.y; As[ac+2][64+ar] = av1.z; As[ac+3][64+ar] = av1.w;
        *(float4*)&Bs[wr][wc]     = wv0;
        *(float4*)&Bs[wr + 8][wc] = wv1;
        __syncthreads();
        if (k0 + 16 < kDIM) {
            av0 = *(const float4*)(xA  + k0 + 16);
            av1 = *(const float4*)(xA2 + k0 + 16);
            wv0 = *(const float4*)(wB  + (size_t)(k0 + 16) * ldw);
            wv1 = *(const float4*)(wB2 + (size_t)(k0 + 16) * ldw);
        }
#pragma unroll
        for (int kk = 0; kk < 16; ++kk) {
            float4 a0 = *(const float4*)&As[kk][ty * 4];
            float4 a1 = *(const float4*)&As[kk][64 + ty * 4];
            float4 b0 = *(const float4*)&Bs[kk][tx * 4];
            float4 b1 = *(const float4*)&Bs[kk][64 + tx * 4];
            float a[8] = {a0.x,a0.y,a0.z,a0.w,a1.x,a1.y,a1.z,a1.w};
            float b[8] = {b0.x,b0.y,b0.z,b0.w,b1.x,b1.y,b1.z,b1.w};
#pragma unroll
            for (int i = 0; i < 8; ++i)
#pragma unroll
                for (int j = 0; j < 8; ++j) acc[i][j] += a[i] * b[j];
        }
    }
#pragma unroll
    for (int hi = 0; hi < 2; ++hi)
#pragma unroll
    for (int ii = 0; ii < 4; ++ii) {
        int row  = bm + hi * 64 + ty * 4 + ii;
        int brow = row >> 11;
        int irow = row & (kN - 1);
        int i = hi * 4 + ii;
#pragma unroll
        for (int jh = 0; jh < 2; ++jh) {
            int col  = nn0 + jh * 64 + tx * 4;
            int hcol = col / hd;
            int dd   = col - hcol * hd;
            int jb = jh * 4;
            size_t idx = (((size_t)brow * kH + hcol) * kN + irow) * hd + dd;
            if (is_q) {
                float4 o4 = make_float4(acc[i][jb]*kScale, acc[i][jb+1]*kScale,
                                        acc[i][jb+2]*kScale, acc[i][jb+3]*kScale);
                *(float4*)&qo[idx] = o4;
            } else {
                ushort4 o4;
                o4.x = f2b(acc[i][jb]);   o4.y = f2b(acc[i][jb+1]);
                o4.z = f2b(acc[i][jb+2]); o4.w = f2b(acc[i][jb+3]);
                *(ushort4*)&o16[idx] = o4;
            }
        }
    }
}

// ---------------------------------------------------------------------------
// c[b,h,i] = sum_d (q_scaled[b,h,i,d] + rpb[h,d]) * W_rel[h*DK+d]   (q fp32)
// ---------------------------------------------------------------------------
__global__ __launch_bounds__(256) void c_kernel(
    const float* __restrict__ q, const float* __restrict__ Wrel,
    const float* __restrict__ rpb, float* __restrict__ c)
{
    int gid  = blockIdx.x * 256 + threadIdx.x;
    int wid  = gid >> 6;
    int lane = gid & 63;
    int h = (wid >> 11) & (kH - 1);
    float val = (q[(size_t)wid * kDK + lane] + rpb[h * kDK + lane]) * Wrel[h * kDK + lane];
#pragma unroll
    for (int off = 32; off; off >>= 1) val += __shfl_down(val, off, 64);
    if (lane == 0) c[wid] = val;
}

// ---------------------------------------------------------------------------
// Flash attention, rank-1 relative term: logits = (q+rcb)·k + (j-i)*c_i
// q fp32; k,v bf16 in; attn_out bf16 out. BM=64, BN=32, 256 threads.
// ---------------------------------------------------------------------------
__global__ __launch_bounds__(256) void flash_attn(
    const float* __restrict__ q,                 // [B*H, N, DK] fp32
    const unsigned short* __restrict__ k,        // [B*H, N, DK] bf16
    const unsigned short* __restrict__ v,        // [B*H, N, DV] bf16
    const float* __restrict__ crel,              // [B*H, N]
    const float* __restrict__ rcb,               // [H, DK]
    unsigned short* __restrict__ ao)             // [B*N, H*DV] bf16
{
    __shared__ float Qs[64][68];      // 17408 B
    __shared__ float Ks[32][68];      //  8704 B
    __shared__ float Ps[64][40];      // 10240 B
    __shared__ float Vs[32][192];     // 24576 B
    __shared__ float cs[64];
    __shared__ float alpha_s[64];
    __shared__ float tsum_s[64];

    const int tid = threadIdx.x;
    const int bh  = blockIdx.y;
    const int h   = bh & (kH - 1);
    const int i0  = blockIdx.x * 64;
    const int tx  = tid & 15, ty = tid >> 4;

    // stage Q (+ content bias), fp32
#pragma unroll
    for (int u = 0; u < 4; ++u) {
        int row = u * 16 + ty;
        int d0  = tx * 4;
        float4 qv = *(const float4*)&q[((size_t)bh * kN + i0 + row) * kDK + d0];
        float4 bb = *(const float4*)&rcb[h * kDK + d0];
        qv.x += bb.x; qv.y += bb.y; qv.z += bb.z; qv.w += bb.w;
        *(float4*)&Qs[row][d0] = qv;
    }
    if (tid < 64) cs[tid] = crel[(size_t)bh * kN + i0 + tid];

    float m_reg[4];
#pragma unroll
    for (int i = 0; i < 4; ++i) m_reg[i] = -INFINITY;

    const int orow = tid >> 2;
    const int ocol = (tid & 3) * 48;
    float O[48];
#pragma unroll
    for (int i = 0; i < 48; ++i) O[i] = 0.f;
    float l_reg = 0.f;

    for (int j0 = 0; j0 < kN; j0 += 32) {
        __syncthreads();   // prev PV done reading Ps/Vs
        // stage K tile (32 x 64) bf16 -> fp32
#pragma unroll
        for (int u = 0; u < 2; ++u) {
            int row = u * 16 + ty;
            int d0  = tx * 4;
            ushort4 kv = *(const ushort4*)&k[((size_t)bh * kN + j0 + row) * kDK + d0];
            Ks[row][d0+0] = b2f(kv.x); Ks[row][d0+1] = b2f(kv.y);
            Ks[row][d0+2] = b2f(kv.z); Ks[row][d0+3] = b2f(kv.w);
        }
        // stage V tile (32 x 192) bf16 -> fp32, 8 elems per pass
#pragma unroll
        for (int u = 0; u < 3; ++u) {
            int row = tid >> 3;
            int c0  = (tid & 7) * 8 + u * 64;
            uint4 w4 = *(const uint4*)&v[((size_t)bh * kN + row + j0) * kDV + c0];
            float2 p0 = up2(w4.x), p1 = up2(w4.y), p2 = up2(w4.z), p3 = up2(w4.w);
            *(float2*)&Vs[row][c0+0] = p0; *(float2*)&Vs[row][c0+2] = p1;
            *(float2*)&Vs[row][c0+4] = p2; *(float2*)&Vs[row][c0+6] = p3;
        }
        __syncthreads();
        // S = (Q+rcb) K^T
        float s[4][2];
#pragma unroll
        for (int i = 0; i < 4; ++i) { s[i][0] = 0.f; s[i][1] = 0.f; }
#pragma unroll
        for (int d0 = 0; d0 < 64; d0 += 4) {
            float4 qv[4], kv[2];
#pragma unroll
            for (int i = 0; i < 4; ++i) qv[i] = *(const float4*)&Qs[ty + 16 * i][d0];
#pragma unroll
            for (int j = 0; j < 2; ++j) kv[j] = *(const float4*)&Ks[tx + 16 * j][d0];
#pragma unroll
            for (int i = 0; i < 4; ++i)
#pragma unroll
                for (int j = 0; j < 2; ++j)
                    s[i][j] += qv[i].x*kv[j].x + qv[i].y*kv[j].y + qv[i].z*kv[j].z + qv[i].w*kv[j].w;
        }
        // rel term + online softmax in registers; write P / alpha / tsum
#pragma unroll
        for (int i = 0; i < 4; ++i) {
            int row = ty + 16 * i;
            float cr = cs[row];
            float gi = (float)(i0 + row);
#pragma unroll
            for (int j = 0; j < 2; ++j)
                s[i][j] += ((float)(j0 + tx + 16 * j) - gi) * cr;
            float mloc = fmaxf(s[i][0], s[i][1]);
            mloc = fmaxf(mloc, __shfl_xor(mloc, 1, 64));
            mloc = fmaxf(mloc, __shfl_xor(mloc, 2, 64));
            mloc = fmaxf(mloc, __shfl_xor(mloc, 4, 64));
            mloc = fmaxf(mloc, __shfl_xor(mloc, 8, 64));
            float mnew  = fmaxf(m_reg[i], mloc);
            float alpha = __expf(m_reg[i] - mnew);
            m_reg[i] = mnew;
            float p0 = __expf(s[i][0] - mnew);
            float p1 = __expf(s[i][1] - mnew);
            Ps[row][tx]      = p0;
            Ps[row][tx + 16] = p1;
            float ts = p0 + p1;
            ts += __shfl_xor(ts, 1, 64);
            ts += __shfl_xor(ts, 2, 64);
            ts += __shfl_xor(ts, 4, 64);
            ts += __shfl_xor(ts, 8, 64);
            if (tx == 0) { alpha_s[row] = alpha; tsum_s[row] = ts; }
        }
        __syncthreads();
        // PV accumulate
        float alpha = alpha_s[orow];
        l_reg = l_reg * alpha + tsum_s[orow];
#pragma unroll
        for (int i = 0; i < 48; ++i) O[i] *= alpha;
#pragma unroll
        for (int j4 = 0; j4 < 8; ++j4) {
            float4 p4 = *(const float4*)&Ps[orow][j4 * 4];
            float pa[4] = {p4.x, p4.y, p4.z, p4.w};
#pragma unroll
            for (int jj = 0; jj < 4; ++jj) {
                float p = pa[jj];
                const float* vrow = &Vs[j4 * 4 + jj][ocol];
#pragma unroll
                for (int u = 0; u < 12; ++u) {
                    float4 vv = *(const float4*)&vrow[u * 4];
                    O[u*4+0] += p * vv.x;
                    O[u*4+1] += p * vv.y;
                    O[u*4+2] += p * vv.z;
                    O[u*4+3] += p * vv.w;
                }
            }
        }
    }
    // write attn_out [b, i, h*DV + c] as bf16
    float inv = 1.0f / l_reg;
    const int brow = bh >> 3;
    size_t obase = ((size_t)brow * kN + i0 + orow) * kHDV + h * kDV + ocol;
#pragma unroll
    for (int u = 0; u < 12; ++u) {
        ushort4 o4;
        o4.x = f2b(O[u*4+0]*inv); o4.y = f2b(O[u*4+1]*inv);
        o4.z = f2b(O[u*4+2]*inv); o4.w = f2b(O[u*4+3]*inv);
        *(ushort4*)&ao[obase + u * 4] = o4;
    }
}

// ---------------------------------------------------------------------------
// out = attn_out(bf16) @ Wo + bo
// ---------------------------------------------------------------------------
__global__ __launch_bounds__(256) void out_gemm(
    const unsigned short* __restrict__ A,   // [B*N, HDV] bf16
    const float* __restrict__ W,            // [HDV, DIM]
    const float* __restrict__ bias,
    float* __restrict__ out)                // [B*N, DIM]
{
    __shared__ float As[16][132];
    __shared__ float Bs[16][132];
    const int tid = threadIdx.x;
    const int bm = blockIdx.y * 128;
    const int bn = blockIdx.x * 128;
    const int tx = tid & 15, ty = tid >> 4;
    const int ar = tid >> 2, ac = (tid & 3) << 2;
    const int wr = tid >> 5, wc = (tid & 31) << 2;

    const unsigned short* pA  = A + (size_t)(bm + ar) * kHDV + ac;
    const unsigned short* pA2 = A + (size_t)(bm + 64 + ar) * kHDV + ac;
    const float* pB  = W + (size_t)wr * kDIM + bn + wc;
    const float* pB2 = W + (size_t)(wr + 8) * kDIM + bn + wc;

    ushort4 av0 = *(const ushort4*)pA;
    ushort4 av1 = *(const ushort4*)pA2;
    float4 wv0 = *(const float4*)pB;
    float4 wv1 = *(const float4*)pB2;

    float acc[8][8];
#pragma unroll
    for (int i = 0; i < 8; ++i)
#pragma unroll
        for (int j = 0; j < 8; ++j) acc[i][j] = 0.f;

    for (int k0 = 0; k0 < kHDV; k0 += 16) {
        __syncthreads();
        As[ac+0][ar]    = b2f(av0.x); As[ac+1][ar]    = b2f(av0.y);
        As[ac+2][ar]    = b2f(av0.z); As[ac+3][ar]    = b2f(av0.w);
        As[ac+0][64+ar] = b2f(av1.x); As[ac+1][64+ar] = b2f(av1.y);
        As[ac+2][64+ar] = b2f(av1.z); As[ac+3][64+ar] = b2f(av1.w);
        *(float4*)&Bs[wr][wc]     = wv0;
        *(float4*)&Bs[wr + 8][wc] = wv1;
        __syncthreads();
        if (k0 + 16 < kHDV) {
            av0 = *(const ushort4*)(pA  + k0 + 16);
            av1 = *(const ushort4*)(pA2 + k0 + 16);
            wv0 = *(const float4*)(pB  + (size_t)(k0 + 16) * kDIM);
            wv1 = *(const float4*)(pB2 + (size_t)(k0 + 16) * kDIM);
        }
#pragma unroll
        for (int kk = 0; kk < 16; ++kk) {
            float4 a0 = *(const float4*)&As[kk][ty * 4];
            float4 a1 = *(const float4*)&As[kk][64 + ty * 4];
            float4 b0 = *(const float4*)&Bs[kk][tx * 4];
            float4 b1 = *(const float4*)&Bs[kk][64 + tx * 4];
            float a[8] = {a0.x,a0.y,a0.z,a0.w,a1.x,a1.y,a1.z,a1.w};
            float b[8] = {b0.x,b0.y,b0.z,b0.w,b1.x,b1.y,b1.z,b1.w};
#pragma unroll
            for (int i = 0; i < 8; ++i)
#pragma unroll
                for (int j = 0; j < 8; ++j) acc[i][j] += a[i] * b[j];
        }
    }
#pragma unroll
    for (int hi = 0; hi < 2; ++hi)
#pragma unroll
    for (int ii = 0; ii < 4; ++ii) {
        int row = bm + hi * 64 + ty * 4 + ii;
        int i = hi * 4 + ii;
#pragma unroll
        for (int jh = 0; jh < 2; ++jh) {
            int col = bn + jh * 64 + tx * 4;
            int jb = jh * 4;
            float4 b4 = *(const float4*)&bias[col];
            float4 o4 = make_float4(acc[i][jb] + b4.x, acc[i][jb+1] + b4.y,
                                    acc[i][jb+2] + b4.z, acc[i][jb+3] + b4.w);
            *(float4*)&out[(size_t)row * kDIM + col] = o4;
        }
    }
}

// ---------------------------------------------------------------------------
extern "C" void kernel_launch(void* const* d_in, const int* in_sizes, int n_in,
                              void* d_out, int out_size, void* d_ws, size_t ws_size,
                              hipStream_t stream)
{
    const float* x    = (const float*)d_in[0];
    const float* Wq   = (const float*)d_in[1];
    const float* Wk   = (const float*)d_in[2];
    const float* Wv   = (const float*)d_in[3];
    const float* Wrel = (const float*)d_in[4];
    const float* Wo   = (const float*)d_in[5];
    const float* bo   = (const float*)d_in[6];
    const float* rcb  = (const float*)d_in[7];
    const float* rpb  = (const float*)d_in[8];
    float* out = (float*)d_out;

    // workspace layout: q fp32 | k bf16 | v bf16 | c fp32 | attn_out bf16
    // = 8 + 4 + 12 + 0.125 + 12 = 36.1 MiB
    float*          qw = (float*)d_ws;                    // 2,097,152 f32
    unsigned short* kw = (unsigned short*)(qw + 2097152); // 2,097,152 bf16
    unsigned short* vw = kw + 2097152;                    // 6,291,456 bf16
    float*          cw = (float*)(vw + 6291456);          //    32,768 f32
    unsigned short* aw = (unsigned short*)(cw + 32768);   // 6,291,456 bf16

    dim3 g1((2 * kHDK + kHDV) / 128, (kB * kN) / 128);   // (20, 32)
    qkv_gemm<<<g1, 256, 0, stream>>>(x, Wq, Wk, Wv, qw, kw, vw);

    int crows = kB * kH * kN;
    c_kernel<<<(crows * 64) / 256, 256, 0, stream>>>(qw, Wrel, rpb, cw);

    dim3 g3(kN / 64, kB * kH);                            // (32, 16)
    flash_attn<<<g3, 256, 0, stream>>>(qw, kw, vw, cw, rcb, aw);

    dim3 g4(kDIM / 128, (kB * kN) / 128);                 // (12, 32)
    out_gemm<<<g4, 256, 0, stream>>>(aw, Wo, bo, out);
}

// Round 3
// 438.319 us; speedup vs baseline: 4.1798x; 4.1798x over previous
//
#include <hip/hip_runtime.h>
#include <math.h>

typedef __attribute__((ext_vector_type(8))) short short8;
typedef __attribute__((ext_vector_type(4))) float floatx4;

namespace {
constexpr int kB = 2, kN = 2048, kDIM = 1536, kH = 8, kDK = 64, kDV = 192;
constexpr int kHDV = kH * kDV;   // 1536
constexpr float kScale = 0.125f; // DK^-0.5
}

__device__ __forceinline__ unsigned short f2b(float f) {
    union { float f; unsigned u; } v; v.f = f;
    unsigned r = (v.u + 0x7FFFu + ((v.u >> 16) & 1u)) >> 16;
    return (unsigned short)r;
}

// ---------------------------------------------------------------------------
// convert fp32 weight [1536][Ncols] -> bf16 transposed [Ncols rows][1536]
// (dst pointer is pre-offset to the destination row block)
// ---------------------------------------------------------------------------
__global__ __launch_bounds__(256) void conv_w(
    const float* __restrict__ src, unsigned short* __restrict__ dst, int Ncols)
{
    __shared__ float Ts[32][33];
    const int tx = threadIdx.x & 31, ty = threadIdx.x >> 5;
    const int k0 = blockIdx.x * 32, n0 = blockIdx.y * 32;
#pragma unroll
    for (int p = 0; p < 4; ++p)
        Ts[ty + p * 8][tx] = src[(size_t)(k0 + ty + p * 8) * Ncols + n0 + tx];
    __syncthreads();
#pragma unroll
    for (int p = 0; p < 4; ++p)
        dst[(size_t)(n0 + ty + p * 8) * kDIM + k0 + tx] = f2b(Ts[tx][ty + p * 8]);
}

// ---------------------------------------------------------------------------
// x fp32 -> bf16 (elementwise), 4 elems/thread
// ---------------------------------------------------------------------------
__global__ __launch_bounds__(256) void conv_x(
    const float* __restrict__ x, unsigned short* __restrict__ xb)
{
    int idx = blockIdx.x * 256 + threadIdx.x;   // grid covers exactly total/4
    float4 v = *(const float4*)&x[(size_t)idx * 4];
    ushort4 o; o.x = f2b(v.x); o.y = f2b(v.y); o.z = f2b(v.z); o.w = f2b(v.w);
    *(ushort4*)&xb[(size_t)idx * 4] = o;
}

// ---------------------------------------------------------------------------
// wcm[dim*8+h] = scale * sum_d Wq[dim][h*64+d]*Wrel[h*64+d];  wcm[12288+h]=rpb.Wrel
// ---------------------------------------------------------------------------
__global__ __launch_bounds__(256) void wcm_pre(
    const float* __restrict__ Wq, const float* __restrict__ Wrel,
    const float* __restrict__ rpb, float* __restrict__ wcm)
{
    int gid = blockIdx.x * 256 + threadIdx.x;
    if (gid < 12288) {
        int dim = gid >> 3, h = gid & 7;
        float s = 0.f;
#pragma unroll 8
        for (int d = 0; d < 64; ++d)
            s += Wq[(size_t)dim * 512 + h * 64 + d] * Wrel[h * 64 + d];
        wcm[gid] = s * kScale;
    } else if (gid < 12296) {
        int h = gid - 12288;
        float s = 0.f;
#pragma unroll 8
        for (int d = 0; d < 64; ++d) s += rpb[h * 64 + d] * Wrel[h * 64 + d];
        wcm[12288 + h] = s;
    }
}

// ---------------------------------------------------------------------------
// c[b,h,i] = x[row] . wcm[:,h] + cconst[h]   (fp32, exact path for rel term)
// ---------------------------------------------------------------------------
__global__ __launch_bounds__(256) void c_gemm(
    const float* __restrict__ x, const float* __restrict__ wcm,
    float* __restrict__ cw)
{
    int task = blockIdx.x * 256 + threadIdx.x;   // 32768 tasks
    int row = task >> 3, h = task & 7;
    const float* xr = x + (size_t)row * kDIM;
    float a0 = 0.f, a1 = 0.f, a2 = 0.f, a3 = 0.f;
    for (int d = 0; d < kDIM; d += 4) {
        float4 xv = *(const float4*)&xr[d];
        a0 += xv.x * wcm[(d + 0) * 8 + h];
        a1 += xv.y * wcm[(d + 1) * 8 + h];
        a2 += xv.z * wcm[(d + 2) * 8 + h];
        a3 += xv.w * wcm[(d + 3) * 8 + h];
    }
    cw[(size_t)((row >> 11) * 8 + h) * kN + (row & 2047)] =
        a0 + a1 + a2 + a3 + wcm[12288 + h];
}

// ---------------------------------------------------------------------------
// QKV GEMM (bf16 MFMA): [4096 x 1536] @ [1536 x 2560] -> q_att/k/v layouts
// 128x128 tile, BK=64, 4 waves (2x2), 4x4 16x16 subtiles per wave.
// ---------------------------------------------------------------------------
__global__ __launch_bounds__(256) void mm_qkv(
    const unsigned short* __restrict__ xb,   // [4096][1536] bf16
    const unsigned short* __restrict__ wt,   // [2560][1536] bf16 (B^T)
    const float* __restrict__ rcb,           // [H*DK] fp32
    unsigned short* __restrict__ qo,         // [BH][N][64]
    unsigned short* __restrict__ ko,         // [BH][N][64]
    unsigned short* __restrict__ vo)         // [BH][N][192]
{
    __shared__ unsigned short A_lds[128 * 72];
    __shared__ unsigned short B_lds[128 * 72];
    const int tid = threadIdx.x;
    const int wave = tid >> 6, lane = tid & 63, lm = lane & 15, lg = lane >> 4;
    const int bm = blockIdx.y * 128, bn = blockIdx.x * 128;
    const int mb = (wave >> 1) * 64, nb = (wave & 1) * 64;

    floatx4 acc[4][4];
#pragma unroll
    for (int i = 0; i < 4; ++i)
#pragma unroll
        for (int j = 0; j < 4; ++j)
#pragma unroll
            for (int r = 0; r < 4; ++r) acc[i][j][r] = 0.f;

    const int srow = tid >> 3, scc = (tid & 7) * 8;   // + p*32 rows
    short8 ra[4], rb[4];
#pragma unroll
    for (int p = 0; p < 4; ++p) {
        ra[p] = *(const short8*)&xb[(size_t)(bm + srow + p * 32) * kDIM + scc];
        rb[p] = *(const short8*)&wt[(size_t)(bn + srow + p * 32) * kDIM + scc];
    }

    for (int kt = 0; kt < 24; ++kt) {
        __syncthreads();
#pragma unroll
        for (int p = 0; p < 4; ++p) {
            *(short8*)&A_lds[(srow + p * 32) * 72 + scc] = ra[p];
            *(short8*)&B_lds[(srow + p * 32) * 72 + scc] = rb[p];
        }
        __syncthreads();
        if (kt < 23) {
            int k0 = (kt + 1) * 64;
#pragma unroll
            for (int p = 0; p < 4; ++p) {
                ra[p] = *(const short8*)&xb[(size_t)(bm + srow + p * 32) * kDIM + k0 + scc];
                rb[p] = *(const short8*)&wt[(size_t)(bn + srow + p * 32) * kDIM + k0 + scc];
            }
        }
#pragma unroll
        for (int ks = 0; ks < 2; ++ks) {
            short8 af[4], bf[4];
#pragma unroll
            for (int mi = 0; mi < 4; ++mi)
                af[mi] = *(const short8*)&A_lds[(mb + mi * 16 + lm) * 72 + lg * 8 + 32 * ks];
#pragma unroll
            for (int ni = 0; ni < 4; ++ni)
                bf[ni] = *(const short8*)&B_lds[(nb + ni * 16 + lm) * 72 + lg * 8 + 32 * ks];
#pragma unroll
            for (int mi = 0; mi < 4; ++mi)
#pragma unroll
                for (int ni = 0; ni < 4; ++ni)
                    acc[mi][ni] = __builtin_amdgcn_mfma_f32_16x16x32_bf16(
                        af[mi], bf[ni], acc[mi][ni], 0, 0, 0);
        }
    }

    // epilogue: block-uniform q/k/v dispatch (512 % 128 == 0)
#pragma unroll
    for (int mi = 0; mi < 4; ++mi)
#pragma unroll
        for (int ni = 0; ni < 4; ++ni)
#pragma unroll
            for (int r = 0; r < 4; ++r) {
                int row = bm + mb + mi * 16 + lg * 4 + r;
                int b = row >> 11, i = row & 2047;
                int col = bn + nb + ni * 16 + lm;
                float v = acc[mi][ni][r];
                if (bn < 512) {
                    int h = col >> 6, d = col & 63;
                    qo[((size_t)(b * 8 + h) * kN + i) * kDK + d] =
                        f2b(v * kScale + rcb[h * 64 + d]);
                } else if (bn < 1024) {
                    int c2 = col - 512, h = c2 >> 6, d = c2 & 63;
                    ko[((size_t)(b * 8 + h) * kN + i) * kDK + d] = f2b(v);
                } else {
                    int c2 = col - 1024, h = c2 / 192, d = c2 - h * 192;
                    vo[((size_t)(b * 8 + h) * kN + i) * kDV + d] = f2b(v);
                }
            }
}

// ---------------------------------------------------------------------------
// V transpose: [bh][i][192] -> [bh][192][i]  (bf16)
// ---------------------------------------------------------------------------
__global__ __launch_bounds__(256) void vtrans(
    const unsigned short* __restrict__ vw, unsigned short* __restrict__ vt)
{
    __shared__ unsigned short Ts[32][33];
    const int tx = threadIdx.x & 31, ty = threadIdx.x >> 5;
    const int i0 = blockIdx.x * 32, d0 = blockIdx.y * 32, bh = blockIdx.z;
#pragma unroll
    for (int p = 0; p < 4; ++p)
        Ts[ty + p * 8][tx] = vw[((size_t)bh * kN + i0 + ty + p * 8) * kDV + d0 + tx];
    __syncthreads();
#pragma unroll
    for (int p = 0; p < 4; ++p)
        vt[((size_t)bh * kDV + d0 + ty + p * 8) * kN + i0 + tx] = Ts[tx][ty + p * 8];
}

// ---------------------------------------------------------------------------
// Flash attention, MFMA. 4 waves x 16 q-rows, KV tile = 64.
// logits = (q*scale+rcb).k + (j-i)*c_i ; online softmax in registers.
// ---------------------------------------------------------------------------
__global__ __launch_bounds__(256) void flash_attn(
    const unsigned short* __restrict__ q,    // [BH][N][64] bf16 (scaled, +rcb)
    const unsigned short* __restrict__ k,    // [BH][N][64] bf16
    const unsigned short* __restrict__ vt,   // [BH][192][N] bf16 (transposed)
    const float* __restrict__ crel,          // [BH][N] fp32
    unsigned short* __restrict__ ao)         // [B*N][1536] bf16
{
    __shared__ unsigned short K_lds[64 * 72];    //  9216 B
    __shared__ unsigned short V_lds[192 * 72];   // 27648 B
    __shared__ unsigned short P_lds[4 * 16 * 72];//  9216 B
    __shared__ float cs[64];

    const int tid = threadIdx.x;
    const int wave = tid >> 6, lane = tid & 63, lm = lane & 15, lg = lane >> 4;
    const int bh = blockIdx.y;
    const int i0 = blockIdx.x * 64;

    // Q A-fragments straight from global (wave's 16 rows, 2 k-steps)
    short8 qA[2];
    {
        const size_t qb = ((size_t)bh * kN + i0 + wave * 16 + lm) * kDK + lg * 8;
        qA[0] = *(const short8*)&q[qb];
        qA[1] = *(const short8*)&q[qb + 32];
    }
    if (tid < 64) cs[tid] = crel[(size_t)bh * kN + i0 + tid];

    floatx4 o4[12];
#pragma unroll
    for (int nd = 0; nd < 12; ++nd)
#pragma unroll
        for (int r = 0; r < 4; ++r) o4[nd][r] = 0.f;
    float m_[4] = {-INFINITY, -INFINITY, -INFINITY, -INFINITY};
    float l_[4] = {0.f, 0.f, 0.f, 0.f};

    const unsigned short* kb = k + (size_t)bh * kN * kDK;
    const unsigned short* vb = vt + (size_t)bh * kDV * kN;
    const int pbase = wave * 16 * 72;

    for (int t = 0; t < 32; ++t) {
        const int j0 = t * 64;
        __syncthreads();   // prev tile fully consumed
        // stage K tile [64][64]
#pragma unroll
        for (int p = 0; p < 2; ++p) {
            int c = tid + p * 256;
            int row = c >> 3, cc = (c & 7) * 8;
            *(short8*)&K_lds[row * 72 + cc] =
                *(const short8*)&kb[(size_t)(j0 + row) * kDK + cc];
        }
        // stage V^T tile [192][64]
#pragma unroll
        for (int p = 0; p < 6; ++p) {
            int c = tid + p * 256;
            int row = c >> 3, cc = (c & 7) * 8;
            *(short8*)&V_lds[row * 72 + cc] =
                *(const short8*)&vb[(size_t)row * kN + j0 + cc];
        }
        __syncthreads();

        // S = Q K^T : 4 col-subtiles x 2 k-steps
        floatx4 s4[4];
#pragma unroll
        for (int st = 0; st < 4; ++st) {
#pragma unroll
            for (int r = 0; r < 4; ++r) s4[st][r] = 0.f;
#pragma unroll
            for (int ks = 0; ks < 2; ++ks) {
                short8 kf = *(const short8*)&K_lds[(st * 16 + lm) * 72 + lg * 8 + 32 * ks];
                s4[st] = __builtin_amdgcn_mfma_f32_16x16x32_bf16(qA[ks], kf, s4[st], 0, 0, 0);
            }
        }

        // rel term + online softmax; P -> per-wave LDS (bf16)
        float alpha[4];
#pragma unroll
        for (int r = 0; r < 4; ++r) {
            const int lrow = wave * 16 + lg * 4 + r;
            const float ci = cs[lrow];
            const float gi = (float)(i0 + lrow);
            float sv[4];
#pragma unroll
            for (int st = 0; st < 4; ++st)
                sv[st] = s4[st][r] + ((float)(j0 + st * 16 + lm) - gi) * ci;
            float mx = fmaxf(fmaxf(sv[0], sv[1]), fmaxf(sv[2], sv[3]));
            mx = fmaxf(mx, __shfl_xor(mx, 1, 64));
            mx = fmaxf(mx, __shfl_xor(mx, 2, 64));
            mx = fmaxf(mx, __shfl_xor(mx, 4, 64));
            mx = fmaxf(mx, __shfl_xor(mx, 8, 64));
            float mnew = fmaxf(m_[r], mx);
            alpha[r] = __expf(m_[r] - mnew);
            m_[r] = mnew;
            float ts = 0.f;
#pragma unroll
            for (int st = 0; st < 4; ++st) {
                float pv = __expf(sv[st] - mnew);
                ts += pv;
                P_lds[pbase + (lg * 4 + r) * 72 + st * 16 + lm] = f2b(pv);
            }
            ts += __shfl_xor(ts, 1, 64);
            ts += __shfl_xor(ts, 2, 64);
            ts += __shfl_xor(ts, 4, 64);
            ts += __shfl_xor(ts, 8, 64);
            l_[r] = l_[r] * alpha[r] + ts;
        }

        // rescale O
#pragma unroll
        for (int nd = 0; nd < 12; ++nd)
#pragma unroll
            for (int r = 0; r < 4; ++r) o4[nd][r] *= alpha[r];

        // O += P V : A = P (wave-private), B = V^T rows
        short8 pa[2];
        pa[0] = *(const short8*)&P_lds[pbase + lm * 72 + lg * 8];
        pa[1] = *(const short8*)&P_lds[pbase + lm * 72 + lg * 8 + 32];
#pragma unroll
        for (int nd = 0; nd < 12; ++nd) {
#pragma unroll
            for (int ks = 0; ks < 2; ++ks) {
                short8 vf = *(const short8*)&V_lds[(nd * 16 + lm) * 72 + lg * 8 + 32 * ks];
                o4[nd] = __builtin_amdgcn_mfma_f32_16x16x32_bf16(pa[ks], vf, o4[nd], 0, 0, 0);
            }
        }
    }

    // epilogue: ao[b, i, h*192 + d]
    const int b = bh >> 3, h = bh & 7;
#pragma unroll
    for (int r = 0; r < 4; ++r) {
        float inv = 1.f / l_[r];
        size_t rowbase = ((size_t)b * kN + i0 + wave * 16 + lg * 4 + r) * (size_t)kHDV
                         + h * kDV;
#pragma unroll
        for (int nd = 0; nd < 12; ++nd)
            ao[rowbase + nd * 16 + lm] = f2b(o4[nd][r] * inv);
    }
}

// ---------------------------------------------------------------------------
// out = aw(bf16) @ Wo + bo  (MFMA, same structure as mm_qkv), fp32 out
// ---------------------------------------------------------------------------
__global__ __launch_bounds__(256) void mm_out(
    const unsigned short* __restrict__ aw,   // [4096][1536] bf16
    const unsigned short* __restrict__ wot,  // [1536][1536] bf16 (B^T)
    const float* __restrict__ bias,
    float* __restrict__ out)                 // [4096][1536] fp32
{
    __shared__ unsigned short A_lds[128 * 72];
    __shared__ unsigned short B_lds[128 * 72];
    const int tid = threadIdx.x;
    const int wave = tid >> 6, lane = tid & 63, lm = lane & 15, lg = lane >> 4;
    const int bm = blockIdx.y * 128, bn = blockIdx.x * 128;
    const int mb = (wave >> 1) * 64, nb = (wave & 1) * 64;

    floatx4 acc[4][4];
#pragma unroll
    for (int i = 0; i < 4; ++i)
#pragma unroll
        for (int j = 0; j < 4; ++j)
#pragma unroll
            for (int r = 0; r < 4; ++r) acc[i][j][r] = 0.f;

    const int srow = tid >> 3, scc = (tid & 7) * 8;
    short8 ra[4], rb[4];
#pragma unroll
    for (int p = 0; p < 4; ++p) {
        ra[p] = *(const short8*)&aw[(size_t)(bm + srow + p * 32) * kDIM + scc];
        rb[p] = *(const short8*)&wot[(size_t)(bn + srow + p * 32) * kDIM + scc];
    }

    for (int kt = 0; kt < 24; ++kt) {
        __syncthreads();
#pragma unroll
        for (int p = 0; p < 4; ++p) {
            *(short8*)&A_lds[(srow + p * 32) * 72 + scc] = ra[p];
            *(short8*)&B_lds[(srow + p * 32) * 72 + scc] = rb[p];
        }
        __syncthreads();
        if (kt < 23) {
            int k0 = (kt + 1) * 64;
#pragma unroll
            for (int p = 0; p < 4; ++p) {
                ra[p] = *(const short8*)&aw[(size_t)(bm + srow + p * 32) * kDIM + k0 + scc];
                rb[p] = *(const short8*)&wot[(size_t)(bn + srow + p * 32) * kDIM + k0 + scc];
            }
        }
#pragma unroll
        for (int ks = 0; ks < 2; ++ks) {
            short8 af[4], bf[4];
#pragma unroll
            for (int mi = 0; mi < 4; ++mi)
                af[mi] = *(const short8*)&A_lds[(mb + mi * 16 + lm) * 72 + lg * 8 + 32 * ks];
#pragma unroll
            for (int ni = 0; ni < 4; ++ni)
                bf[ni] = *(const short8*)&B_lds[(nb + ni * 16 + lm) * 72 + lg * 8 + 32 * ks];
#pragma unroll
            for (int mi = 0; mi < 4; ++mi)
#pragma unroll
                for (int ni = 0; ni < 4; ++ni)
                    acc[mi][ni] = __builtin_amdgcn_mfma_f32_16x16x32_bf16(
                        af[mi], bf[ni], acc[mi][ni], 0, 0, 0);
        }
    }

#pragma unroll
    for (int mi = 0; mi < 4; ++mi)
#pragma unroll
        for (int ni = 0; ni < 4; ++ni)
#pragma unroll
            for (int r = 0; r < 4; ++r) {
                int row = bm + mb + mi * 16 + lg * 4 + r;
                int col = bn + nb + ni * 16 + lm;
                out[(size_t)row * kDIM + col] = acc[mi][ni][r] + bias[col];
            }
}

// ---------------------------------------------------------------------------
extern "C" void kernel_launch(void* const* d_in, const int* in_sizes, int n_in,
                              void* d_out, int out_size, void* d_ws, size_t ws_size,
                              hipStream_t stream)
{
    const float* x    = (const float*)d_in[0];
    const float* Wq   = (const float*)d_in[1];
    const float* Wk   = (const float*)d_in[2];
    const float* Wv   = (const float*)d_in[3];
    const float* Wrel = (const float*)d_in[4];
    const float* Wo   = (const float*)d_in[5];
    const float* bo   = (const float*)d_in[6];
    const float* rcb  = (const float*)d_in[7];
    const float* rpb  = (const float*)d_in[8];
    float* out = (float*)d_out;

    // workspace (bytes, all 256-aligned); aliases: vt->xb, aw->vw, Wot->Wt
    char* w = (char*)d_ws;
    unsigned short* xb  = (unsigned short*)(w);              // 12,582,912 B (later: vt)
    unsigned short* wt  = (unsigned short*)(w + 12582912);   //  7,864,320 B (later: Wot)
    unsigned short* qw  = (unsigned short*)(w + 20447232);   //  4,194,304 B
    unsigned short* kw  = (unsigned short*)(w + 24641536);   //  4,194,304 B
    unsigned short* vw  = (unsigned short*)(w + 28835840);   // 12,582,912 B (later: aw)
    float*          cw  = (float*)(w + 41418752);            //    131,072 B
    float*          wcm = (float*)(w + 41549824);            //     49,184 B
    unsigned short* vtp = xb;        // V^T, reuses xb after mm_qkv
    unsigned short* awp = vw;        // attn_out, reuses vw after vtrans
    unsigned short* wot = wt;        // Wo^T, reuses wt after mm_qkv

    // weight converts (before qkv): Wq->rows 0-511, Wk->512-1023, Wv->1024-2559
    { dim3 g(48, 16);  conv_w<<<g, 256, 0, stream>>>(Wq, wt,               512); }
    { dim3 g(48, 16);  conv_w<<<g, 256, 0, stream>>>(Wk, wt + 512  * 1536, 512); }
    { dim3 g(48, 48);  conv_w<<<g, 256, 0, stream>>>(Wv, wt + 1024 * 1536, 1536); }
    conv_x<<<6144, 256, 0, stream>>>(x, xb);
    wcm_pre<<<49, 256, 0, stream>>>(Wq, Wrel, rpb, wcm);
    c_gemm<<<128, 256, 0, stream>>>(x, wcm, cw);

    { dim3 g(20, 32); mm_qkv<<<g, 256, 0, stream>>>(xb, wt, rcb, qw, kw, vw); }

    // after qkv: wt and xb are dead -> reuse
    { dim3 g(48, 48); conv_w<<<g, 256, 0, stream>>>(Wo, wot, 1536); }
    { dim3 g(64, 6, 16); vtrans<<<g, 256, 0, stream>>>(vw, vtp); }

    { dim3 g(32, 16); flash_attn<<<g, 256, 0, stream>>>(qw, kw, vtp, cw, awp); }

    { dim3 g(12, 32); mm_out<<<g, 256, 0, stream>>>(awp, wot, bo, out); }
}

// Round 4
// 335.257 us; speedup vs baseline: 5.4648x; 1.3074x over previous
//
#include <hip/hip_runtime.h>
#include <math.h>

typedef __attribute__((ext_vector_type(8))) short short8;
typedef __attribute__((ext_vector_type(4))) float floatx4;

namespace {
constexpr int kB = 2, kN = 2048, kDIM = 1536, kH = 8, kDK = 64, kDV = 192;
constexpr int kHDV = kH * kDV;   // 1536
constexpr float kScale = 0.125f; // DK^-0.5
}

__device__ __forceinline__ unsigned short f2b(float f) {
    union { float f; unsigned u; } v; v.f = f;
    unsigned r = (v.u + 0x7FFFu + ((v.u >> 16) & 1u)) >> 16;
    return (unsigned short)r;
}

// ---------------------------------------------------------------------------
// convert fp32 weight [1536][Ncols] -> bf16 transposed [Ncols rows][1536]
// ---------------------------------------------------------------------------
__global__ __launch_bounds__(256) void conv_w(
    const float* __restrict__ src, unsigned short* __restrict__ dst, int Ncols)
{
    __shared__ float Ts[32][33];
    const int tx = threadIdx.x & 31, ty = threadIdx.x >> 5;
    const int k0 = blockIdx.x * 32, n0 = blockIdx.y * 32;
#pragma unroll
    for (int p = 0; p < 4; ++p)
        Ts[ty + p * 8][tx] = src[(size_t)(k0 + ty + p * 8) * Ncols + n0 + tx];
    __syncthreads();
#pragma unroll
    for (int p = 0; p < 4; ++p)
        dst[(size_t)(n0 + ty + p * 8) * kDIM + k0 + tx] = f2b(Ts[tx][ty + p * 8]);
}

// ---------------------------------------------------------------------------
// x fp32 -> bf16 (elementwise), 4 elems/thread
// ---------------------------------------------------------------------------
__global__ __launch_bounds__(256) void conv_x(
    const float* __restrict__ x, unsigned short* __restrict__ xb)
{
    int idx = blockIdx.x * 256 + threadIdx.x;
    float4 v = *(const float4*)&x[(size_t)idx * 4];
    ushort4 o; o.x = f2b(v.x); o.y = f2b(v.y); o.z = f2b(v.z); o.w = f2b(v.w);
    *(ushort4*)&xb[(size_t)idx * 4] = o;
}

// ---------------------------------------------------------------------------
// wcm_t[h*1536+dim] = scale * sum_d Wq[dim][h*64+d]*Wrel[h*64+d]
// wcm_t[12288+h]    = rpb[h].Wrel[h]
// ---------------------------------------------------------------------------
__global__ __launch_bounds__(256) void wcm_pre(
    const float* __restrict__ Wq, const float* __restrict__ Wrel,
    const float* __restrict__ rpb, float* __restrict__ wcm)
{
    int gid = blockIdx.x * 256 + threadIdx.x;
    if (gid < 12288) {
        int dim = gid >> 3, h = gid & 7;
        float s = 0.f;
#pragma unroll 8
        for (int d = 0; d < 64; ++d)
            s += Wq[(size_t)dim * 512 + h * 64 + d] * Wrel[h * 64 + d];
        wcm[h * kDIM + dim] = s * kScale;   // transposed store
    } else if (gid < 12296) {
        int h = gid - 12288;
        float s = 0.f;
#pragma unroll 8
        for (int d = 0; d < 64; ++d) s += rpb[h * 64 + d] * Wrel[h * 64 + d];
        wcm[12288 + h] = s;
    }
}

// ---------------------------------------------------------------------------
// c[b,h,i] = x[row].wcm_t[h] + const[h]  — one wave per x-row, fp32 exact.
// 4096 rows -> 1024 blocks x 4 waves. x read once (coalesced float4),
// wcm_t (48 KB) broadcast from L2. 8 butterfly reductions per wave.
// ---------------------------------------------------------------------------
__global__ __launch_bounds__(256) void c_gemm(
    const float* __restrict__ x, const float* __restrict__ wcm,
    float* __restrict__ cw)
{
    const int row  = blockIdx.x * 4 + (threadIdx.x >> 6);
    const int lane = threadIdx.x & 63;
    const float* xr = x + (size_t)row * kDIM;

    float4 xv[6];
#pragma unroll
    for (int c = 0; c < 6; ++c)
        xv[c] = *(const float4*)&xr[c * 256 + lane * 4];

    float acc[8];
#pragma unroll
    for (int h = 0; h < 8; ++h) {
        const float* wr = wcm + h * kDIM;
        float a = 0.f;
#pragma unroll
        for (int c = 0; c < 6; ++c) {
            float4 wv = *(const float4*)&wr[c * 256 + lane * 4];
            a += xv[c].x * wv.x + xv[c].y * wv.y + xv[c].z * wv.z + xv[c].w * wv.w;
        }
        acc[h] = a;
    }
#pragma unroll
    for (int h = 0; h < 8; ++h) {
        float a = acc[h];
        a += __shfl_xor(a, 1, 64);
        a += __shfl_xor(a, 2, 64);
        a += __shfl_xor(a, 4, 64);
        a += __shfl_xor(a, 8, 64);
        a += __shfl_xor(a, 16, 64);
        a += __shfl_xor(a, 32, 64);
        acc[h] = a;
    }
    if (lane == 0) {
        const int b = row >> 11, i = row & 2047;
#pragma unroll
        for (int h = 0; h < 8; ++h)
            cw[(size_t)(b * 8 + h) * kN + i] = acc[h] + wcm[12288 + h];
    }
}

// ---------------------------------------------------------------------------
// QKV GEMM (bf16 MFMA): [4096 x 1536] @ [1536 x 2560] -> q_att/k/v layouts
// 128x128 tile, BK=64, 4 waves (2x2), 4x4 16x16 subtiles per wave.
// ---------------------------------------------------------------------------
__global__ __launch_bounds__(256) void mm_qkv(
    const unsigned short* __restrict__ xb,   // [4096][1536] bf16
    const unsigned short* __restrict__ wt,   // [2560][1536] bf16 (B^T)
    const float* __restrict__ rcb,           // [H*DK] fp32
    unsigned short* __restrict__ qo,         // [BH][N][64]
    unsigned short* __restrict__ ko,         // [BH][N][64]
    unsigned short* __restrict__ vo)         // [BH][N][192]
{
    __shared__ unsigned short A_lds[128 * 72];
    __shared__ unsigned short B_lds[128 * 72];
    const int tid = threadIdx.x;
    const int wave = tid >> 6, lane = tid & 63, lm = lane & 15, lg = lane >> 4;
    const int bm = blockIdx.y * 128, bn = blockIdx.x * 128;
    const int mb = (wave >> 1) * 64, nb = (wave & 1) * 64;

    floatx4 acc[4][4];
#pragma unroll
    for (int i = 0; i < 4; ++i)
#pragma unroll
        for (int j = 0; j < 4; ++j)
#pragma unroll
            for (int r = 0; r < 4; ++r) acc[i][j][r] = 0.f;

    const int srow = tid >> 3, scc = (tid & 7) * 8;
    short8 ra[4], rb[4];
#pragma unroll
    for (int p = 0; p < 4; ++p) {
        ra[p] = *(const short8*)&xb[(size_t)(bm + srow + p * 32) * kDIM + scc];
        rb[p] = *(const short8*)&wt[(size_t)(bn + srow + p * 32) * kDIM + scc];
    }

    for (int kt = 0; kt < 24; ++kt) {
        __syncthreads();
#pragma unroll
        for (int p = 0; p < 4; ++p) {
            *(short8*)&A_lds[(srow + p * 32) * 72 + scc] = ra[p];
            *(short8*)&B_lds[(srow + p * 32) * 72 + scc] = rb[p];
        }
        __syncthreads();
        if (kt < 23) {
            int k0 = (kt + 1) * 64;
#pragma unroll
            for (int p = 0; p < 4; ++p) {
                ra[p] = *(const short8*)&xb[(size_t)(bm + srow + p * 32) * kDIM + k0 + scc];
                rb[p] = *(const short8*)&wt[(size_t)(bn + srow + p * 32) * kDIM + k0 + scc];
            }
        }
#pragma unroll
        for (int ks = 0; ks < 2; ++ks) {
            short8 af[4], bf[4];
#pragma unroll
            for (int mi = 0; mi < 4; ++mi)
                af[mi] = *(const short8*)&A_lds[(mb + mi * 16 + lm) * 72 + lg * 8 + 32 * ks];
#pragma unroll
            for (int ni = 0; ni < 4; ++ni)
                bf[ni] = *(const short8*)&B_lds[(nb + ni * 16 + lm) * 72 + lg * 8 + 32 * ks];
#pragma unroll
            for (int mi = 0; mi < 4; ++mi)
#pragma unroll
                for (int ni = 0; ni < 4; ++ni)
                    acc[mi][ni] = __builtin_amdgcn_mfma_f32_16x16x32_bf16(
                        af[mi], bf[ni], acc[mi][ni], 0, 0, 0);
        }
    }

#pragma unroll
    for (int mi = 0; mi < 4; ++mi)
#pragma unroll
        for (int ni = 0; ni < 4; ++ni)
#pragma unroll
            for (int r = 0; r < 4; ++r) {
                int row = bm + mb + mi * 16 + lg * 4 + r;
                int b = row >> 11, i = row & 2047;
                int col = bn + nb + ni * 16 + lm;
                float v = acc[mi][ni][r];
                if (bn < 512) {
                    int h = col >> 6, d = col & 63;
                    qo[((size_t)(b * 8 + h) * kN + i) * kDK + d] =
                        f2b(v * kScale + rcb[h * 64 + d]);
                } else if (bn < 1024) {
                    int c2 = col - 512, h = c2 >> 6, d = c2 & 63;
                    ko[((size_t)(b * 8 + h) * kN + i) * kDK + d] = f2b(v);
                } else {
                    int c2 = col - 1024, h = c2 / 192, d = c2 - h * 192;
                    vo[((size_t)(b * 8 + h) * kN + i) * kDV + d] = f2b(v);
                }
            }
}

// ---------------------------------------------------------------------------
// V transpose: [bh][i][192] -> [bh][192][i]  (bf16)
// ---------------------------------------------------------------------------
__global__ __launch_bounds__(256) void vtrans(
    const unsigned short* __restrict__ vw, unsigned short* __restrict__ vt)
{
    __shared__ unsigned short Ts[32][33];
    const int tx = threadIdx.x & 31, ty = threadIdx.x >> 5;
    const int i0 = blockIdx.x * 32, d0 = blockIdx.y * 32, bh = blockIdx.z;
#pragma unroll
    for (int p = 0; p < 4; ++p)
        Ts[ty + p * 8][tx] = vw[((size_t)bh * kN + i0 + ty + p * 8) * kDV + d0 + tx];
    __syncthreads();
#pragma unroll
    for (int p = 0; p < 4; ++p)
        vt[((size_t)bh * kDV + d0 + ty + p * 8) * kN + i0 + tx] = Ts[tx][ty + p * 8];
}

// ---------------------------------------------------------------------------
// Flash attention, MFMA. 4 waves x 16 q-rows, KV tile = 64.
// ---------------------------------------------------------------------------
__global__ __launch_bounds__(256) void flash_attn(
    const unsigned short* __restrict__ q,    // [BH][N][64] bf16 (scaled, +rcb)
    const unsigned short* __restrict__ k,    // [BH][N][64] bf16
    const unsigned short* __restrict__ vt,   // [BH][192][N] bf16 (transposed)
    const float* __restrict__ crel,          // [BH][N] fp32
    unsigned short* __restrict__ ao)         // [B*N][1536] bf16
{
    __shared__ unsigned short K_lds[64 * 72];
    __shared__ unsigned short V_lds[192 * 72];
    __shared__ unsigned short P_lds[4 * 16 * 72];
    __shared__ float cs[64];

    const int tid = threadIdx.x;
    const int wave = tid >> 6, lane = tid & 63, lm = lane & 15, lg = lane >> 4;
    const int bh = blockIdx.y;
    const int i0 = blockIdx.x * 64;

    short8 qA[2];
    {
        const size_t qb = ((size_t)bh * kN + i0 + wave * 16 + lm) * kDK + lg * 8;
        qA[0] = *(const short8*)&q[qb];
        qA[1] = *(const short8*)&q[qb + 32];
    }
    if (tid < 64) cs[tid] = crel[(size_t)bh * kN + i0 + tid];

    floatx4 o4[12];
#pragma unroll
    for (int nd = 0; nd < 12; ++nd)
#pragma unroll
        for (int r = 0; r < 4; ++r) o4[nd][r] = 0.f;
    float m_[4] = {-INFINITY, -INFINITY, -INFINITY, -INFINITY};
    float l_[4] = {0.f, 0.f, 0.f, 0.f};

    const unsigned short* kb = k + (size_t)bh * kN * kDK;
    const unsigned short* vb = vt + (size_t)bh * kDV * kN;
    const int pbase = wave * 16 * 72;

    for (int t = 0; t < 32; ++t) {
        const int j0 = t * 64;
        __syncthreads();
#pragma unroll
        for (int p = 0; p < 2; ++p) {
            int c = tid + p * 256;
            int row = c >> 3, cc = (c & 7) * 8;
            *(short8*)&K_lds[row * 72 + cc] =
                *(const short8*)&kb[(size_t)(j0 + row) * kDK + cc];
        }
#pragma unroll
        for (int p = 0; p < 6; ++p) {
            int c = tid + p * 256;
            int row = c >> 3, cc = (c & 7) * 8;
            *(short8*)&V_lds[row * 72 + cc] =
                *(const short8*)&vb[(size_t)row * kN + j0 + cc];
        }
        __syncthreads();

        floatx4 s4[4];
#pragma unroll
        for (int st = 0; st < 4; ++st) {
#pragma unroll
            for (int r = 0; r < 4; ++r) s4[st][r] = 0.f;
#pragma unroll
            for (int ks = 0; ks < 2; ++ks) {
                short8 kf = *(const short8*)&K_lds[(st * 16 + lm) * 72 + lg * 8 + 32 * ks];
                s4[st] = __builtin_amdgcn_mfma_f32_16x16x32_bf16(qA[ks], kf, s4[st], 0, 0, 0);
            }
        }

        float alpha[4];
#pragma unroll
        for (int r = 0; r < 4; ++r) {
            const int lrow = wave * 16 + lg * 4 + r;
            const float ci = cs[lrow];
            const float gi = (float)(i0 + lrow);
            float sv[4];
#pragma unroll
            for (int st = 0; st < 4; ++st)
                sv[st] = s4[st][r] + ((float)(j0 + st * 16 + lm) - gi) * ci;
            float mx = fmaxf(fmaxf(sv[0], sv[1]), fmaxf(sv[2], sv[3]));
            mx = fmaxf(mx, __shfl_xor(mx, 1, 64));
            mx = fmaxf(mx, __shfl_xor(mx, 2, 64));
            mx = fmaxf(mx, __shfl_xor(mx, 4, 64));
            mx = fmaxf(mx, __shfl_xor(mx, 8, 64));
            float mnew = fmaxf(m_[r], mx);
            alpha[r] = __expf(m_[r] - mnew);
            m_[r] = mnew;
            float ts = 0.f;
#pragma unroll
            for (int st = 0; st < 4; ++st) {
                float pv = __expf(sv[st] - mnew);
                ts += pv;
                P_lds[pbase + (lg * 4 + r) * 72 + st * 16 + lm] = f2b(pv);
            }
            ts += __shfl_xor(ts, 1, 64);
            ts += __shfl_xor(ts, 2, 64);
            ts += __shfl_xor(ts, 4, 64);
            ts += __shfl_xor(ts, 8, 64);
            l_[r] = l_[r] * alpha[r] + ts;
        }

#pragma unroll
        for (int nd = 0; nd < 12; ++nd)
#pragma unroll
            for (int r = 0; r < 4; ++r) o4[nd][r] *= alpha[r];

        short8 pa[2];
        pa[0] = *(const short8*)&P_lds[pbase + lm * 72 + lg * 8];
        pa[1] = *(const short8*)&P_lds[pbase + lm * 72 + lg * 8 + 32];
#pragma unroll
        for (int nd = 0; nd < 12; ++nd) {
#pragma unroll
            for (int ks = 0; ks < 2; ++ks) {
                short8 vf = *(const short8*)&V_lds[(nd * 16 + lm) * 72 + lg * 8 + 32 * ks];
                o4[nd] = __builtin_amdgcn_mfma_f32_16x16x32_bf16(pa[ks], vf, o4[nd], 0, 0, 0);
            }
        }
    }

    const int b = bh >> 3, h = bh & 7;
#pragma unroll
    for (int r = 0; r < 4; ++r) {
        float inv = 1.f / l_[r];
        size_t rowbase = ((size_t)b * kN + i0 + wave * 16 + lg * 4 + r) * (size_t)kHDV
                         + h * kDV;
#pragma unroll
        for (int nd = 0; nd < 12; ++nd)
            ao[rowbase + nd * 16 + lm] = f2b(o4[nd][r] * inv);
    }
}

// ---------------------------------------------------------------------------
// out = aw(bf16) @ Wo + bo  (MFMA), fp32 out
// ---------------------------------------------------------------------------
__global__ __launch_bounds__(256) void mm_out(
    const unsigned short* __restrict__ aw,   // [4096][1536] bf16
    const unsigned short* __restrict__ wot,  // [1536][1536] bf16 (B^T)
    const float* __restrict__ bias,
    float* __restrict__ out)                 // [4096][1536] fp32
{
    __shared__ unsigned short A_lds[128 * 72];
    __shared__ unsigned short B_lds[128 * 72];
    const int tid = threadIdx.x;
    const int wave = tid >> 6, lane = tid & 63, lm = lane & 15, lg = lane >> 4;
    const int bm = blockIdx.y * 128, bn = blockIdx.x * 128;
    const int mb = (wave >> 1) * 64, nb = (wave & 1) * 64;

    floatx4 acc[4][4];
#pragma unroll
    for (int i = 0; i < 4; ++i)
#pragma unroll
        for (int j = 0; j < 4; ++j)
#pragma unroll
            for (int r = 0; r < 4; ++r) acc[i][j][r] = 0.f;

    const int srow = tid >> 3, scc = (tid & 7) * 8;
    short8 ra[4], rb[4];
#pragma unroll
    for (int p = 0; p < 4; ++p) {
        ra[p] = *(const short8*)&aw[(size_t)(bm + srow + p * 32) * kDIM + scc];
        rb[p] = *(const short8*)&wot[(size_t)(bn + srow + p * 32) * kDIM + scc];
    }

    for (int kt = 0; kt < 24; ++kt) {
        __syncthreads();
#pragma unroll
        for (int p = 0; p < 4; ++p) {
            *(short8*)&A_lds[(srow + p * 32) * 72 + scc] = ra[p];
            *(short8*)&B_lds[(srow + p * 32) * 72 + scc] = rb[p];
        }
        __syncthreads();
        if (kt < 23) {
            int k0 = (kt + 1) * 64;
#pragma unroll
            for (int p = 0; p < 4; ++p) {
                ra[p] = *(const short8*)&aw[(size_t)(bm + srow + p * 32) * kDIM + k0 + scc];
                rb[p] = *(const short8*)&wot[(size_t)(bn + srow + p * 32) * kDIM + k0 + scc];
            }
        }
#pragma unroll
        for (int ks = 0; ks < 2; ++ks) {
            short8 af[4], bf[4];
#pragma unroll
            for (int mi = 0; mi < 4; ++mi)
                af[mi] = *(const short8*)&A_lds[(mb + mi * 16 + lm) * 72 + lg * 8 + 32 * ks];
#pragma unroll
            for (int ni = 0; ni < 4; ++ni)
                bf[ni] = *(const short8*)&B_lds[(nb + ni * 16 + lm) * 72 + lg * 8 + 32 * ks];
#pragma unroll
            for (int mi = 0; mi < 4; ++mi)
#pragma unroll
                for (int ni = 0; ni < 4; ++ni)
                    acc[mi][ni] = __builtin_amdgcn_mfma_f32_16x16x32_bf16(
                        af[mi], bf[ni], acc[mi][ni], 0, 0, 0);
        }
    }

#pragma unroll
    for (int mi = 0; mi < 4; ++mi)
#pragma unroll
        for (int ni = 0; ni < 4; ++ni)
#pragma unroll
            for (int r = 0; r < 4; ++r) {
                int row = bm + mb + mi * 16 + lg * 4 + r;
                int col = bn + nb + ni * 16 + lm;
                out[(size_t)row * kDIM + col] = acc[mi][ni][r] + bias[col];
            }
}

// ---------------------------------------------------------------------------
extern "C" void kernel_launch(void* const* d_in, const int* in_sizes, int n_in,
                              void* d_out, int out_size, void* d_ws, size_t ws_size,
                              hipStream_t stream)
{
    const float* x    = (const float*)d_in[0];
    const float* Wq   = (const float*)d_in[1];
    const float* Wk   = (const float*)d_in[2];
    const float* Wv   = (const float*)d_in[3];
    const float* Wrel = (const float*)d_in[4];
    const float* Wo   = (const float*)d_in[5];
    const float* bo   = (const float*)d_in[6];
    const float* rcb  = (const float*)d_in[7];
    const float* rpb  = (const float*)d_in[8];
    float* out = (float*)d_out;

    char* w = (char*)d_ws;
    unsigned short* xb  = (unsigned short*)(w);              // 12,582,912 B (later: vt)
    unsigned short* wt  = (unsigned short*)(w + 12582912);   //  7,864,320 B (later: Wot)
    unsigned short* qw  = (unsigned short*)(w + 20447232);   //  4,194,304 B
    unsigned short* kw  = (unsigned short*)(w + 24641536);   //  4,194,304 B
    unsigned short* vw  = (unsigned short*)(w + 28835840);   // 12,582,912 B (later: aw)
    float*          cw  = (float*)(w + 41418752);            //    131,072 B
    float*          wcm = (float*)(w + 41549824);            //     49,184 B
    unsigned short* vtp = xb;
    unsigned short* awp = vw;
    unsigned short* wot = wt;

    { dim3 g(48, 16);  conv_w<<<g, 256, 0, stream>>>(Wq, wt,               512); }
    { dim3 g(48, 16);  conv_w<<<g, 256, 0, stream>>>(Wk, wt + 512  * 1536, 512); }
    { dim3 g(48, 48);  conv_w<<<g, 256, 0, stream>>>(Wv, wt + 1024 * 1536, 1536); }
    conv_x<<<6144, 256, 0, stream>>>(x, xb);
    wcm_pre<<<49, 256, 0, stream>>>(Wq, Wrel, rpb, wcm);
    c_gemm<<<1024, 256, 0, stream>>>(x, wcm, cw);

    { dim3 g(20, 32); mm_qkv<<<g, 256, 0, stream>>>(xb, wt, rcb, qw, kw, vw); }

    { dim3 g(48, 48); conv_w<<<g, 256, 0, stream>>>(Wo, wot, 1536); }
    { dim3 g(64, 6, 16); vtrans<<<g, 256, 0, stream>>>(vw, vtp); }

    { dim3 g(32, 16); flash_attn<<<g, 256, 0, stream>>>(qw, kw, vtp, cw, awp); }

    { dim3 g(12, 32); mm_out<<<g, 256, 0, stream>>>(awp, wot, bo, out); }
}